// Round 4
// baseline (235.703 us; speedup 1.0000x reference)
//
#include <hip/hip_runtime.h>
#include <math.h>

// DetectionLoss: per-image Hungarian matching (JV shortest augmenting path,
// float64, transposed to 50 rows x 300 cols) + matched L1 / BCE losses.
// One wave per image. All state in registers; wave-uniform cross-lane traffic
// via v_readlane; argmin via DPP f64 min-reduce. No LDS arrays, no barriers.
// All loops are iteration-bounded (guards are no-ops on the correct path) so
// the kernel can never hang.

#define BB 32
#define NN 300   // predictions (columns after transpose)
#define MM 50    // ground truths (rows after transpose)
#define KPL 5    // columns per lane: j = 5*lane + k, lanes 0..59

__device__ __forceinline__ double softplus_d(double x) {
    return fmax(x, 0.0) + log1p(exp(-fabs(x)));   // stable log(1+e^x)
}

__device__ __forceinline__ double readlane_d(double x, int l) {
    long long bx = __double_as_longlong(x);
    int lo = __builtin_amdgcn_readlane((int)bx, l);
    int hi = __builtin_amdgcn_readlane((int)(bx >> 32), l);
    return __longlong_as_double(((long long)hi << 32) | (unsigned int)lo);
}
__device__ __forceinline__ int readlane_i(int x, int l) {
    return __builtin_amdgcn_readlane(x, l);
}

// Full-wave64 f64 min via DPP; result valid in lane 63.
// row_shr 1/2/4/8: lane i accumulates min over its row-prefix -> lane 15/31/47/63
// hold their row's min. row_bcast15 (rows 1,3): lane31=min(rows0-1),
// lane63=min(rows2-3). row_bcast31 (rows 2,3): lane63=min(all).
// Invalid/masked lanes keep old = +INF (identity for min).
__device__ __forceinline__ double wave_min_f64(double x) {
#define DPP_STEP(CTRL, RM) { \
    long long b_ = __double_as_longlong(x); \
    int lo_ = __builtin_amdgcn_update_dpp(0, (int)b_, CTRL, RM, 0xF, false); \
    int hi_ = __builtin_amdgcn_update_dpp(0x7FF00000, (int)(b_ >> 32), CTRL, RM, 0xF, false); \
    double t_ = __longlong_as_double(((long long)hi_ << 32) | (unsigned int)lo_); \
    x = fmin(x, t_); }
    DPP_STEP(0x111, 0xF)   // row_shr:1
    DPP_STEP(0x112, 0xF)   // row_shr:2
    DPP_STEP(0x114, 0xF)   // row_shr:4
    DPP_STEP(0x118, 0xF)   // row_shr:8
    DPP_STEP(0x142, 0xA)   // row_bcast:15 -> rows 1,3
    DPP_STEP(0x143, 0xC)   // row_bcast:31 -> rows 2,3
#undef DPP_STEP
    return x;
}

__global__ __launch_bounds__(64) void lsa_loss_kernel(
    const float* __restrict__ pred_c,   // [B,N,2] f32
    const float* __restrict__ conf,     // [B,N]   f32
    const float* __restrict__ gt_c,     // [B,M,2] f32
    float* __restrict__ out)            // [5] f32, zeroed before launch
{
    const int b = blockIdx.x;
    const int lane = threadIdx.x;
    const bool owns = lane < (NN / KPL);     // lanes 0..59 own 5 columns each
    const int base_j = KPL * lane;

    // per-column state (registers; all accesses literal-indexed after unroll)
    double px[KPL], py[KPL], cf[KPL], cneg[KPL], v[KPL], sh[KPL];
    int pb[KPL], r4c[KPL];
    int rem;
    // per-row state (lanes 0..49)
    double u = 0.0, gx = 0.0, gy = 0.0;
    int col4row = -1;

#pragma unroll
    for (int k = 0; k < KPL; ++k) {
        int j = base_j + k;
        double vpx = 0.0, vpy = 0.0, vcf = 0.0;
        if (owns) {
            vpx = (double)pred_c[(b*NN + j)*2 + 0];
            vpy = (double)pred_c[(b*NN + j)*2 + 1];
            vcf = (double)conf[b*NN + j];
        }
        px[k] = vpx; py[k] = vpy; cf[k] = vcf;
        cneg[k] = -(1.0 / (1.0 + exp(-vcf)));   // COST_CONF * (-sigmoid)
        v[k] = 0.0;
        r4c[k] = -1;
    }
    if (lane < MM) {
        gx = (double)gt_c[(b*MM + lane)*2 + 0];
        gy = (double)gt_c[(b*MM + lane)*2 + 1];
    }

    for (int cur_row = 0; cur_row < MM; ++cur_row) {
#pragma unroll
        for (int k = 0; k < KPL; ++k) { sh[k] = INFINITY; pb[k] = -1; }
        rem = owns ? 0x1F : 0;
        unsigned long long sr_mask = 0ull;   // uniform
        double min_val = 0.0;
        int i = cur_row;                     // uniform
        int sink = -1;

        // Dijkstra pops: each iteration removes one column, so <= NN pops.
        // The bound is a hang-guard only; it never binds on the correct path.
        for (int pops = 0; pops <= NN && sink < 0; ++pops) {
            sr_mask |= (1ull << i);
            double u_i  = readlane_d(u,  i);
            double gx_i = readlane_d(gx, i);
            double gy_i = readlane_d(gy, i);

            // relax owned remaining columns (pure registers)
#pragma unroll
            for (int k = 0; k < KPL; ++k) {
                if ((rem >> k) & 1) {
                    double cost = 5.0*(fabs(px[k]-gx_i)+fabs(py[k]-gy_i)) + cneg[k];
                    double nc = ((min_val + cost) - u_i) - v[k];
                    if (nc < sh[k]) { sh[k] = nc; pb[k] = i; }
                }
            }

            // local argmin (ascending k, strict < -> smallest k on ties)
            double lbest = INFINITY; int lbestk = 0;
#pragma unroll
            for (int k = 0; k < KPL; ++k)
                if (((rem >> k) & 1) && sh[k] < lbest) { lbest = sh[k]; lbestk = k; }

            // global min via DPP; first-lane tie-break == np.argmin semantics
            double gmin = readlane_d(wave_min_f64(lbest), 63);
            unsigned long long mask = __ballot(lbest == gmin);
            if (mask == 0ull) mask = 1ull;                // hang-guard (never on correct path)
            int srcl = (int)__ffsll(mask) - 1;            // owner lane of best col
            int qj = readlane_i(lbestk, srcl);            // uniform
            int bestj = KPL*srcl + qj;
            min_val = readlane_d(lbest, srcl);            // stored value, exact

            if (lane == srcl) rem &= ~(1 << qj);
            int r4l = qj==0?r4c[0]:qj==1?r4c[1]:qj==2?r4c[2]:qj==3?r4c[3]:r4c[4];
            int r4 = readlane_i(r4l, srcl);
            if (r4 < 0 || r4 >= MM) sink = bestj; else i = r4;
        }

        // dual updates (before augment, as in reference)
        {
            int c  = col4row < 0 ? 0 : col4row;           // divergent gather
            int tc = c / KPL, qc = c - KPL*tc;
            double t0 = __shfl(sh[0], tc, 64);
            double t1 = __shfl(sh[1], tc, 64);
            double t2 = __shfl(sh[2], tc, 64);
            double t3 = __shfl(sh[3], tc, 64);
            double t4 = __shfl(sh[4], tc, 64);
            double shc = qc==0?t0:qc==1?t1:qc==2?t2:qc==3?t3:t4;
            if (lane < MM) {
                if (lane == cur_row) u += min_val;
                else if ((sr_mask >> lane) & 1ull) u += min_val - shc;
            }
        }
#pragma unroll
        for (int k = 0; k < KPL; ++k)
            if (owns && !((rem >> k) & 1))   // SC = columns removed this row
                v[k] -= min_val - sh[k];

        // augmenting-path backtrack (wave-uniform, readlane only; bounded)
        int j = sink < 0 ? 0 : sink;
        for (int step = 0; step <= MM; ++step) {
            int tj = j / KPL, qj = j - KPL*tj;            // uniform
            int pbl = qj==0?pb[0]:qj==1?pb[1]:qj==2?pb[2]:qj==3?pb[3]:pb[4];
            int pi = readlane_i(pbl, tj);                 // uniform
            if (pi < 0 || pi >= MM) break;                // hang-guard
            if (lane == tj) {
                if      (qj==0) r4c[0]=pi; else if (qj==1) r4c[1]=pi;
                else if (qj==2) r4c[2]=pi; else if (qj==3) r4c[3]=pi;
                else            r4c[4]=pi;
            }
            int c_old = readlane_i(col4row, pi);          // uniform
            if (lane == pi) col4row = j;
            j = c_old;
            if (pi == cur_row) break;
            if (j < 0 || j >= NN) break;                  // hang-guard
        }
    }

    // ---- losses from f32 inputs (reference computes loss in f32/jnp) ----
    double lp = 0.0, lo = 0.0, ln = 0.0;
    if (lane < MM) {
        int j = (col4row < 0 || col4row >= NN) ? 0 : col4row;  // matched pred
        float dx = fabsf(pred_c[(b*NN + j)*2 + 0] - gt_c[(b*MM + lane)*2 + 0]);
        float dy = fabsf(pred_c[(b*NN + j)*2 + 1] - gt_c[(b*MM + lane)*2 + 1]);
        lp = (double)dx + (double)dy;
        lo = softplus_d(-(double)conf[b*NN + j]);   // BCE target=1
    }
#pragma unroll
    for (int k = 0; k < KPL; ++k)
        if (owns && r4c[k] < 0)              // unmatched predictions
            ln += softplus_d(cf[k]);
#pragma unroll
    for (int off = 32; off > 0; off >>= 1) {
        lp += __shfl_xor(lp, off, 64);
        lo += __shfl_xor(lo, off, 64);
        ln += __shfl_xor(ln, off, 64);
    }
    if (lane == 0) {
        double cp = 5.0 * (lp / (double)(MM*2))  / (double)BB;  // LAMBDA_POS
        double co = 2.0 * (lo / (double)MM)      / (double)BB;  // LAMBDA_CONF
        double cn = 0.5 * (ln / (double)(NN-MM)) / (double)BB;  // LAMBDA_NOOBJ
        atomicAdd(&out[0], (float)cp);
        atomicAdd(&out[1], (float)co);
        atomicAdd(&out[2], (float)cn);
        atomicAdd(&out[3], (float)(cp + co + cn));
        if (b == 0) out[4] = 50.0f;          // n_matched = M
    }
}

extern "C" void kernel_launch(void* const* d_in, const int* in_sizes, int n_in,
                              void* d_out, int out_size, void* d_ws, size_t ws_size,
                              hipStream_t stream) {
    const float* pred_c = (const float*)d_in[0];   // [32,300,2]
    // d_in[1] = pred_logits (unused by reference)
    const float* conf   = (const float*)d_in[2];   // [32,300]
    const float* gt_c   = (const float*)d_in[3];   // [32,50,2]
    // d_in[4] = gt_classes (unused by reference)
    float* out = (float*)d_out;                    // 5 scalars

    hipMemsetAsync(out, 0, 5*sizeof(float), stream);   // d_out poisoned 0xAA
    lsa_loss_kernel<<<BB, 64, 0, stream>>>(pred_c, conf, gt_c, out);
}